// Round 4
// baseline (753.547 us; speedup 1.0000x reference)
//
#include <hip/hip_runtime.h>
#include <hip/hip_bf16.h>
#include <cstdint>

// Problem constants (B=2, N=2048 -> T=4096 tokens)
#define TTOK  4096
#define CDIM  1024
#define FFDIM 4096
#define NEXP  8

// Fast-path workspace layout (needs >= 137 MiB):
//   [0,64)            counts[8]   (memset 0 each launch)
//   [64, ..)          offsets[9]
//   [4K, 4K+128K)     btok[8][4096]
//   [132K, 132K+128K) bgate[8][4096]
//   [1MB, 9MB)        xb : x as bf16 [4096,1024]
//   [9MB, 73MB)       Wb : bf16 weights, shared between passes (W1 then W2), 64 MiB
//   [73MB, 137MB)     H  : gelu(X W1^T + b1) bf16, compacted [8192, 4096], 64 MiB

typedef short short8 __attribute__((ext_vector_type(8)));   // 8 bf16 in 4 VGPRs
typedef float f32x4 __attribute__((ext_vector_type(4)));

__device__ __forceinline__ unsigned short f2bf(float f) {
    unsigned int u = __float_as_uint(f);
    u = u + 0x7fffu + ((u >> 16) & 1u);   // round-to-nearest-even
    return (unsigned short)(u >> 16);
}

// async global -> LDS, 16 bytes per lane. LDS dest MUST be wave-uniform base + lane*16.
__device__ __forceinline__ void gl_lds16(const unsigned short* g, unsigned short* l) {
    __builtin_amdgcn_global_load_lds(
        (const __attribute__((address_space(1))) unsigned int*)g,
        (__attribute__((address_space(3))) unsigned int*)l, 16, 0, 0);
}

// Row-pair-interleaved swizzled LDS offset (elements) for a [256][32] bf16 tile.
// Element (row, k=kq*8..) lives at line=row>>1 (128B lines), chunk
// cp = (((row&1)<<2)|kq) ^ (line&7).  Conflict-free for the MFMA frag read
// pattern, and linear-writable by global_load_lds with a pre-swizzled per-lane
// GLOBAL source (rule: swizzle both sides or neither).
__device__ __forceinline__ int swz_off(int row, int kq) {
    const int line = row >> 1;
    const int cp = ((((row & 1) << 2) | kq) ^ (line & 7));
    return line * 64 + cp * 8;
}

#define SBAR() do { __builtin_amdgcn_sched_barrier(0); \
                    __builtin_amdgcn_s_barrier();      \
                    __builtin_amdgcn_sched_barrier(0); } while (0)

// ---------------- fp32 -> bf16 cast (x and weights) ----------------
__global__ void cast_kernel(const float* __restrict__ src, unsigned short* __restrict__ dst) {
    int i = blockIdx.x * blockDim.x + threadIdx.x;   // n/4 threads, exact division
    float4 v = reinterpret_cast<const float4*>(src)[i];
    ushort4 o;
    o.x = f2bf(v.x); o.y = f2bf(v.y); o.z = f2bf(v.z); o.w = f2bf(v.w);
    reinterpret_cast<ushort4*>(dst)[i] = o;
}

// ---------------- router: logits -> softmax -> top2 -> bucket scatter ----------------
__global__ void router_kernel(const float* __restrict__ x, const float* __restrict__ rw,
                              int* __restrict__ counts, int* __restrict__ btok,
                              float* __restrict__ bgate) {
    const int wave = threadIdx.x >> 6;
    const int lane = threadIdx.x & 63;
    const int t = blockIdx.x * 4 + wave;
    const float* xr = x + (size_t)t * CDIM;

    float acc[NEXP];
#pragma unroll
    for (int e = 0; e < NEXP; e++) acc[e] = 0.f;
    for (int c = lane; c < CDIM; c += 64) {
        float xv = xr[c];
#pragma unroll
        for (int e = 0; e < NEXP; e++) acc[e] += xv * rw[e * CDIM + c];
    }
#pragma unroll
    for (int e = 0; e < NEXP; e++) {
#pragma unroll
        for (int off = 32; off > 0; off >>= 1) acc[e] += __shfl_down(acc[e], off, 64);
    }
    if (lane == 0) {
        float mx = acc[0];
#pragma unroll
        for (int e = 1; e < NEXP; e++) mx = fmaxf(mx, acc[e]);
        float p[NEXP]; float s = 0.f;
#pragma unroll
        for (int e = 0; e < NEXP; e++) { p[e] = expf(acc[e] - mx); s += p[e]; }
        int i0 = 0;
#pragma unroll
        for (int e = 1; e < NEXP; e++) if (p[e] > p[i0]) i0 = e;
        int i1 = (i0 == 0) ? 1 : 0;
#pragma unroll
        for (int e = 0; e < NEXP; e++) if (e != i0 && p[e] > p[i1]) i1 = e;
        float pr0 = p[i0] / s, pr1 = p[i1] / s;
        float rs = 1.f / (pr0 + pr1 + 1e-9f);
        float w0 = pr0 * rs, w1 = pr1 * rs;
        int pos = atomicAdd(&counts[i0], 1);
        btok[i0 * TTOK + pos] = t; bgate[i0 * TTOK + pos] = w0;
        pos = atomicAdd(&counts[i1], 1);
        btok[i1 * TTOK + pos] = t; bgate[i1 * TTOK + pos] = w1;
    }
}

__global__ void offsets_kernel(const int* __restrict__ counts, int* __restrict__ offsets) {
    if (threadIdx.x == 0 && blockIdx.x == 0) {
        int s = 0;
        for (int e = 0; e < NEXP; e++) { offsets[e] = s; s += counts[e]; }
        offsets[NEXP] = s;
    }
}

// ===== PIPELINED FAST PATH =====
// 256x256 tile, BK=32, 4-deep LDS ring (4 x 32KB = 128KB), counted vmcnt(8)
// (never drained to 0 in the main loop), raw s_barrier + sched_barrier(0)
// pins, 2 phases x 16 MFMA per K-tile with s_setprio around the MFMA cluster.
// 8 waves = 2m x 4n, each wave owns a 128x64 output sub-tile (acc[8][4] f32x4).
//
// EXPERT->XCD REMAP: default HW XCD assignment is linear-block-id % 8.
// We remap roles so linear_id % 8 == expert: all blocks of expert e land on
// XCD e, so the 4 m-blocks sharing a B-panel and the 4-16 n-blocks sharing an
// A-row-panel co-reside on one XCD's L2 -> staging becomes L2-hit (~200cy)
// instead of L3/HBM-miss (~900cy), which the ring's ~2-iteration prefetch
// lead can actually cover.  Bijective remap: correctness-neutral.

// pass A: H = gelu(X W1b^T + b1)
__global__ __launch_bounds__(512, 2) void gemm1p_kernel(
    const unsigned short* __restrict__ xb, const unsigned short* __restrict__ w1b,
    const float* __restrict__ b1, const int* __restrict__ counts,
    const int* __restrict__ offsets, const int* __restrict__ btok,
    unsigned short* __restrict__ H) {
    // grid (16, 16, 8) = 2048 blocks; remap: e = lin&7 (XCD), s = lin>>3,
    // n_tile = s>>4 (16 FF panels), m_tile = s&15.
    const int lin = blockIdx.x + 16 * (blockIdx.y + 16 * blockIdx.z);
    const int e = lin & 7;
    const int s = lin >> 3;
    const int cnt = counts[e];
    const int m0 = (s & 15) * 256;
    if (m0 >= cnt) return;
    const int n0 = (s >> 4) * 256;     // FF columns
    const int po = offsets[e];
    const int NT = CDIM / 32;          // 32 K-tiles

    __shared__ uint4 smem4[8192];      // 128 KB
    unsigned short* S = (unsigned short*)smem4;

    const int tid = threadIdx.x;
    const int wid = tid >> 6, lane = tid & 63;
    const int lm = lane & 15, kq = lane >> 4;
    const int wr = wid >> 2, wc = wid & 3;

    // ---- staging sources (pre-swizzled global addresses) ----
    const int sline = tid >> 3;                   // 0..63
    const int c128s = (tid & 7) ^ (sline & 7);    // chunk this thread deposits
    const int prty  = c128s >> 2;                 // row parity
    const int skc   = (c128s & 3) << 3;           // k-element offset
    const int ar0 = min(m0 + (sline << 1) + prty, cnt - 1);
    const int ar1 = min(m0 + 128 + (sline << 1) + prty, cnt - 1);
    const unsigned short* asrc0 = xb + (size_t)btok[e * TTOK + ar0] * CDIM + skc;
    const unsigned short* asrc1 = xb + (size_t)btok[e * TTOK + ar1] * CDIM + skc;
    const unsigned short* bsrc0 = w1b + ((size_t)e * FFDIM + n0 + (sline << 1) + prty) * CDIM + skc;
    const unsigned short* bsrc1 = bsrc0 + (size_t)128 * CDIM;

    // ---- fragment LDS offsets (within slot, elements) ----
    int offA[8], offB[4];
#pragma unroll
    for (int f = 0; f < 8; f++) offA[f] = swz_off(wr * 128 + f * 16 + lm, kq);
#pragma unroll
    for (int g = 0; g < 4; g++) offB[g] = swz_off(wc * 64 + g * 16 + lm, kq);

    f32x4 acc[8][4];
#pragma unroll
    for (int f = 0; f < 8; f++)
#pragma unroll
        for (int g = 0; g < 4; g++) { f32x4 z = {0.f, 0.f, 0.f, 0.f}; acc[f][g] = z; }

    // ---- prologue: stage tiles 0,1,2 into slots 0,1,2 ----
#pragma unroll
    for (int tt = 0; tt < 3; tt++) {
        unsigned short* Sa = S + tt * 16384;
        unsigned short* Sb = Sa + 8192;
        const int ko = tt * 32;
        gl_lds16(asrc0 + ko, Sa + tid * 8);
        gl_lds16(bsrc0 + ko, Sb + tid * 8);
        gl_lds16(asrc1 + ko, Sa + (512 + tid) * 8);
        gl_lds16(bsrc1 + ko, Sb + (512 + tid) * 8);
    }
    asm volatile("s_waitcnt vmcnt(8)" ::: "memory");   // tile 0 landed; 1,2 in flight
    SBAR();

    for (int t = 0; t < NT; ++t) {
        unsigned short* Ab = S + (t & 3) * 16384;
        unsigned short* Bb = Ab + 8192;
        int ts = t + 3; if (ts >= NT) ts -= NT;        // wrapped: data unused, keeps vmcnt uniform
        unsigned short* Sa = S + (ts & 3) * 16384;     // NT % 4 == 0 -> slot == (t+3)&3
        unsigned short* Sb = Sa + 8192;
        const int ko = ts * 32;

        short8 bf[4];
        // ---- phase 0: m-frags 0..3 ----
        {
            short8 af[4];
#pragma unroll
            for (int f = 0; f < 4; f++) af[f] = *reinterpret_cast<const short8*>(&Ab[offA[f]]);
#pragma unroll
            for (int g = 0; g < 4; g++) bf[g] = *reinterpret_cast<const short8*>(&Bb[offB[g]]);
            gl_lds16(asrc0 + ko, Sa + tid * 8);
            gl_lds16(bsrc0 + ko, Sb + tid * 8);
            SBAR();
            __builtin_amdgcn_s_setprio(1);
#pragma unroll
            for (int f = 0; f < 4; f++)
#pragma unroll
                for (int g = 0; g < 4; g++)
                    acc[f][g] = __builtin_amdgcn_mfma_f32_16x16x32_bf16(af[f], bf[g], acc[f][g], 0, 0, 0);
            __builtin_amdgcn_s_setprio(0);
            SBAR();
        }
        // ---- phase 1: m-frags 4..7 ----
        {
            short8 af[4];
#pragma unroll
            for (int f = 0; f < 4; f++) af[f] = *reinterpret_cast<const short8*>(&Ab[offA[4 + f]]);
            gl_lds16(asrc1 + ko, Sa + (512 + tid) * 8);
            gl_lds16(bsrc1 + ko, Sb + (512 + tid) * 8);
            asm volatile("s_waitcnt vmcnt(8)" ::: "memory");   // tile t+1 fully landed
            SBAR();
            __builtin_amdgcn_s_setprio(1);
#pragma unroll
            for (int f = 0; f < 4; f++)
#pragma unroll
                for (int g = 0; g < 4; g++)
                    acc[4 + f][g] = __builtin_amdgcn_mfma_f32_16x16x32_bf16(af[f], bf[g], acc[4 + f][g], 0, 0, 0);
            __builtin_amdgcn_s_setprio(0);
            SBAR();
        }
    }

    // ---- epilogue: bias + GELU + bf16 pack, repack via LDS, coalesced store ----
    asm volatile("s_waitcnt vmcnt(0)" ::: "memory");   // drain wrapped dummy stages
    __syncthreads();                                   // LDS ring dead; reuse for repack

    float bias[4];
#pragma unroll
    for (int g = 0; g < 4; g++) bias[g] = b1[e * FFDIM + n0 + wc * 64 + g * 16 + lm];

    unsigned short* Cs = S;   // 256x256 bf16 = 128KB, chunk-XOR swizzled vs row
#pragma unroll
    for (int f = 0; f < 8; f++) {
#pragma unroll
        for (int r = 0; r < 4; r++) {
            const int row = wr * 128 + f * 16 + kq * 4 + r;
#pragma unroll
            for (int g = 0; g < 4; g++) {
                const int col = wc * 64 + g * 16 + lm;
                float h = acc[f][g][r] + bias[g];
                float gl = 0.5f * h * (1.f + erff(h * 0.70710678118654752f));
                Cs[(row * 256 + col) ^ ((row & 7) << 3)] = f2bf(gl);
            }
        }
    }
    __syncthreads();
#pragma unroll
    for (int q = 0; q < 16; q++) {
        const int cq = q * 512 + tid;
        const int row = cq >> 5;
        const int cc = cq & 31;
        const int mrow = m0 + row;
        if (mrow < cnt)
            *reinterpret_cast<uint4*>(&H[(size_t)(po + mrow) * FFDIM + n0 + cc * 8]) =
                *reinterpret_cast<const uint4*>(&Cs[(row * 256 + cc * 8) ^ ((row & 7) << 3)]);
    }
}

// pass B: out += gate * (H W2b^T + b2), split-K=2, atomic scatter epilogue
__global__ __launch_bounds__(512, 2) void gemm2p_kernel(
    const unsigned short* __restrict__ H, const unsigned short* __restrict__ w2b,
    const float* __restrict__ b2, const int* __restrict__ counts,
    const int* __restrict__ offsets, const int* __restrict__ btok,
    const float* __restrict__ bgate, float* __restrict__ out) {
    // grid (4, 32, 8) = 1024 blocks; remap: e = lin&7 (XCD), s = lin>>3,
    // n_tile = s>>5 (4 C panels), yy = s&31: m_tile = yy>>1, ks = yy&1.
    const int lin = blockIdx.x + 4 * (blockIdx.y + 32 * blockIdx.z);
    const int e = lin & 7;
    const int s = lin >> 3;
    const int cnt = counts[e];
    const int yy = s & 31;
    const int m0 = (yy >> 1) * 256;
    const int ks = yy & 1;             // K split: [ks*2048, ks*2048+2048)
    if (m0 >= cnt) return;
    const int n0 = (s >> 5) * 256;     // C columns
    const int po = offsets[e];
    const int NT = 2048 / 32;          // 64 K-tiles

    __shared__ uint4 smem4[8192];              // 128 KB
    unsigned short* S = (unsigned short*)smem4;

    const int tid = threadIdx.x;
    const int wid = tid >> 6, lane = tid & 63;
    const int lm = lane & 15, kq = lane >> 4;
    const int wr = wid >> 2, wc = wid & 3;

    const int sline = tid >> 3;
    const int c128s = (tid & 7) ^ (sline & 7);
    const int prty  = c128s >> 2;
    const int skc   = (c128s & 3) << 3;
    const int koff  = ks * 2048;
    const int ar0 = min(m0 + (sline << 1) + prty, cnt - 1);
    const int ar1 = min(m0 + 128 + (sline << 1) + prty, cnt - 1);
    const unsigned short* asrc0 = H + (size_t)(po + ar0) * FFDIM + koff + skc;
    const unsigned short* asrc1 = H + (size_t)(po + ar1) * FFDIM + koff + skc;
    const unsigned short* bsrc0 = w2b + ((size_t)e * CDIM + n0 + (sline << 1) + prty) * FFDIM + koff + skc;
    const unsigned short* bsrc1 = bsrc0 + (size_t)128 * FFDIM;

    int offA[8], offB[4];
#pragma unroll
    for (int f = 0; f < 8; f++) offA[f] = swz_off(wr * 128 + f * 16 + lm, kq);
#pragma unroll
    for (int g = 0; g < 4; g++) offB[g] = swz_off(wc * 64 + g * 16 + lm, kq);

    f32x4 acc[8][4];
#pragma unroll
    for (int f = 0; f < 8; f++)
#pragma unroll
        for (int g = 0; g < 4; g++) { f32x4 z = {0.f, 0.f, 0.f, 0.f}; acc[f][g] = z; }

#pragma unroll
    for (int tt = 0; tt < 3; tt++) {
        unsigned short* Sa = S + tt * 16384;
        unsigned short* Sb = Sa + 8192;
        const int ko = tt * 32;
        gl_lds16(asrc0 + ko, Sa + tid * 8);
        gl_lds16(bsrc0 + ko, Sb + tid * 8);
        gl_lds16(asrc1 + ko, Sa + (512 + tid) * 8);
        gl_lds16(bsrc1 + ko, Sb + (512 + tid) * 8);
    }
    asm volatile("s_waitcnt vmcnt(8)" ::: "memory");
    SBAR();

    for (int t = 0; t < NT; ++t) {
        unsigned short* Ab = S + (t & 3) * 16384;
        unsigned short* Bb = Ab + 8192;
        int ts = t + 3; if (ts >= NT) ts -= NT;
        unsigned short* Sa = S + (ts & 3) * 16384;
        unsigned short* Sb = Sa + 8192;
        const int ko = ts * 32;

        short8 bf[4];
        {
            short8 af[4];
#pragma unroll
            for (int f = 0; f < 4; f++) af[f] = *reinterpret_cast<const short8*>(&Ab[offA[f]]);
#pragma unroll
            for (int g = 0; g < 4; g++) bf[g] = *reinterpret_cast<const short8*>(&Bb[offB[g]]);
            gl_lds16(asrc0 + ko, Sa + tid * 8);
            gl_lds16(bsrc0 + ko, Sb + tid * 8);
            SBAR();
            __builtin_amdgcn_s_setprio(1);
#pragma unroll
            for (int f = 0; f < 4; f++)
#pragma unroll
                for (int g = 0; g < 4; g++)
                    acc[f][g] = __builtin_amdgcn_mfma_f32_16x16x32_bf16(af[f], bf[g], acc[f][g], 0, 0, 0);
            __builtin_amdgcn_s_setprio(0);
            SBAR();
        }
        {
            short8 af[4];
#pragma unroll
            for (int f = 0; f < 4; f++) af[f] = *reinterpret_cast<const short8*>(&Ab[offA[4 + f]]);
            gl_lds16(asrc1 + ko, Sa + (512 + tid) * 8);
            gl_lds16(bsrc1 + ko, Sb + (512 + tid) * 8);
            asm volatile("s_waitcnt vmcnt(8)" ::: "memory");
            SBAR();
            __builtin_amdgcn_s_setprio(1);
#pragma unroll
            for (int f = 0; f < 4; f++)
#pragma unroll
                for (int g = 0; g < 4; g++)
                    acc[4 + f][g] = __builtin_amdgcn_mfma_f32_16x16x32_bf16(af[f], bf[g], acc[4 + f][g], 0, 0, 0);
            __builtin_amdgcn_s_setprio(0);
            SBAR();
        }
    }

    asm volatile("s_waitcnt vmcnt(0)" ::: "memory");   // drain dummy stages before epilogue/endpgm

    float bias[4];
#pragma unroll
    for (int g = 0; g < 4; g++)
        bias[g] = (ks == 0) ? b2[e * CDIM + n0 + wc * 64 + g * 16 + lm] : 0.f;

#pragma unroll
    for (int f = 0; f < 8; f++) {
#pragma unroll
        for (int r = 0; r < 4; r++) {
            const int mrow = m0 + wr * 128 + f * 16 + kq * 4 + r;
            if (mrow < cnt) {
                const int tok = btok[e * TTOK + mrow];
                const float g8 = bgate[e * TTOK + mrow];
                float* orow = out + (size_t)tok * CDIM + n0;
#pragma unroll
                for (int g = 0; g < 4; g++)
                    atomicAdd(orow + wc * 64 + g * 16 + lm, g8 * (acc[f][g][r] + bias[g]));
            }
        }
    }
}

// ================= SLOW FALLBACK (round-1 kernels, in-loop fp32->bf16) =================

__global__ __launch_bounds__(256) void gemm1_kernel(
    const unsigned short* __restrict__ xb, const float* __restrict__ w1,
    const float* __restrict__ b1, const int* __restrict__ counts,
    const int* __restrict__ offsets, const int* __restrict__ btok,
    unsigned short* __restrict__ H) {
    const int e = blockIdx.z;
    const int cnt = counts[e];
    const int m0 = blockIdx.y * 128;
    if (m0 >= cnt) return;
    const int n0 = blockIdx.x * 128;
    const int po = offsets[e];

    __shared__ unsigned short As[128][32];
    __shared__ unsigned short Bs[128][32];

    const int tid = threadIdx.x;
    const int wave = tid >> 6, lane = tid & 63;
    const int wm = (wave >> 1) << 6, wn = (wave & 1) << 6;
    const int lm = lane & 15, kq = lane >> 4;

    f32x4 acc[4][4];
#pragma unroll
    for (int i = 0; i < 4; i++)
#pragma unroll
        for (int j = 0; j < 4; j++) { f32x4 z = {0.f, 0.f, 0.f, 0.f}; acc[i][j] = z; }

    const float* w1e = w1 + (size_t)e * FFDIM * CDIM;
    const int arow = tid >> 1;
    const int acolb = (tid & 1) * 16;
    int tokA = -1;
    if (m0 + arow < cnt) tokA = btok[e * TTOK + m0 + arow];
    const int brow = tid >> 1;
    const int bcol = (tid & 1) * 16;

    for (int k0 = 0; k0 < CDIM; k0 += 32) {
        uint4 a0 = {0, 0, 0, 0}, a1 = {0, 0, 0, 0};
        if (tokA >= 0) {
            const uint4* src = reinterpret_cast<const uint4*>(xb + (size_t)tokA * CDIM + k0 + acolb);
            a0 = src[0]; a1 = src[1];
        }
        *reinterpret_cast<uint4*>(&As[arow][acolb]) = a0;
        *reinterpret_cast<uint4*>(&As[arow][acolb + 8]) = a1;
        {
            const float* src = w1e + (size_t)(n0 + brow) * CDIM + k0 + bcol;
            ushort4* dst = reinterpret_cast<ushort4*>(&Bs[brow][bcol]);
#pragma unroll
            for (int q = 0; q < 4; q++) {
                float4 v = reinterpret_cast<const float4*>(src)[q];
                ushort4 o; o.x = f2bf(v.x); o.y = f2bf(v.y); o.z = f2bf(v.z); o.w = f2bf(v.w);
                dst[q] = o;
            }
        }
        __syncthreads();
        short8 af[4], bfr[4];
#pragma unroll
        for (int i = 0; i < 4; i++) af[i] = *reinterpret_cast<const short8*>(&As[wm + i * 16 + lm][kq * 8]);
#pragma unroll
        for (int j = 0; j < 4; j++) bfr[j] = *reinterpret_cast<const short8*>(&Bs[wn + j * 16 + lm][kq * 8]);
#pragma unroll
        for (int i = 0; i < 4; i++)
#pragma unroll
            for (int j = 0; j < 4; j++)
                acc[i][j] = __builtin_amdgcn_mfma_f32_16x16x32_bf16(af[i], bfr[j], acc[i][j], 0, 0, 0);
        __syncthreads();
    }

#pragma unroll
    for (int j = 0; j < 4; j++) {
        const int fcol = n0 + wn + j * 16 + lm;
        const float bias = b1[e * FFDIM + fcol];
#pragma unroll
        for (int i = 0; i < 4; i++) {
#pragma unroll
            for (int r = 0; r < 4; r++) {
                const int mrow = m0 + wm + i * 16 + kq * 4 + r;
                if (mrow < cnt) {
                    float h = acc[i][j][r] + bias;
                    float g = 0.5f * h * (1.f + erff(h * 0.70710678118654752f));
                    H[(size_t)(po + mrow) * FFDIM + fcol] = f2bf(g);
                }
            }
        }
    }
}

__global__ __launch_bounds__(256) void gemm2_kernel(
    const unsigned short* __restrict__ H, const float* __restrict__ w2,
    const float* __restrict__ b2, const int* __restrict__ counts,
    const int* __restrict__ offsets, const int* __restrict__ btok,
    const float* __restrict__ bgate, float* __restrict__ out) {
    const int e = blockIdx.z;
    const int cnt = counts[e];
    const int m0 = blockIdx.y * 128;
    if (m0 >= cnt) return;
    const int n0 = blockIdx.x * 128;
    const int po = offsets[e];

    __shared__ unsigned short As[128][32];
    __shared__ unsigned short Bs[128][32];

    const int tid = threadIdx.x;
    const int wave = tid >> 6, lane = tid & 63;
    const int wm = (wave >> 1) << 6, wn = (wave & 1) << 6;
    const int lm = lane & 15, kq = lane >> 4;

    f32x4 acc[4][4];
#pragma unroll
    for (int i = 0; i < 4; i++)
#pragma unroll
        for (int j = 0; j < 4; j++) { f32x4 z = {0.f, 0.f, 0.f, 0.f}; acc[i][j] = z; }

    const float* w2e = w2 + (size_t)e * CDIM * FFDIM;
    const int arow = tid >> 1;
    const int acolb = (tid & 1) * 16;
    const bool aval = (m0 + arow < cnt);
    const unsigned short* asrc = H + (size_t)(po + m0 + arow) * FFDIM + acolb;
    const int brow = tid >> 1;
    const int bcol = (tid & 1) * 16;

    for (int k0 = 0; k0 < FFDIM; k0 += 32) {
        uint4 a0 = {0, 0, 0, 0}, a1 = {0, 0, 0, 0};
        if (aval) {
            const uint4* src = reinterpret_cast<const uint4*>(asrc + k0);
            a0 = src[0]; a1 = src[1];
        }
        *reinterpret_cast<uint4*>(&As[arow][acolb]) = a0;
        *reinterpret_cast<uint4*>(&As[arow][acolb + 8]) = a1;
        {
            const float* src = w2e + (size_t)(n0 + brow) * FFDIM + k0 + bcol;
            ushort4* dst = reinterpret_cast<ushort4*>(&Bs[brow][bcol]);
#pragma unroll
            for (int q = 0; q < 4; q++) {
                float4 v = reinterpret_cast<const float4*>(src)[q];
                ushort4 o; o.x = f2bf(v.x); o.y = f2bf(v.y); o.z = f2bf(v.z); o.w = f2bf(v.w);
                dst[q] = o;
            }
        }
        __syncthreads();
        short8 af[4], bfr[4];
#pragma unroll
        for (int i = 0; i < 4; i++) af[i] = *reinterpret_cast<const short8*>(&As[wm + i * 16 + lm][kq * 8]);
#pragma unroll
        for (int j = 0; j < 4; j++) bfr[j] = *reinterpret_cast<const short8*>(&Bs[wn + j * 16 + lm][kq * 8]);
#pragma unroll
        for (int i = 0; i < 4; i++)
#pragma unroll
            for (int j = 0; j < 4; j++)
                acc[i][j] = __builtin_amdgcn_mfma_f32_16x16x32_bf16(af[i], bfr[j], acc[i][j], 0, 0, 0);
        __syncthreads();
    }

    float bias[4];
#pragma unroll
    for (int j = 0; j < 4; j++) bias[j] = b2[e * CDIM + n0 + wn + j * 16 + lm];

#pragma unroll
    for (int i = 0; i < 4; i++) {
#pragma unroll
        for (int r = 0; r < 4; r++) {
            const int mrow = m0 + wm + i * 16 + kq * 4 + r;
            if (mrow < cnt) {
                const int tok = btok[e * TTOK + mrow];
                const float g = bgate[e * TTOK + mrow];
                float* orow = out + (size_t)tok * CDIM;
#pragma unroll
                for (int j = 0; j < 4; j++) {
                    const int c = n0 + wn + j * 16 + lm;
                    atomicAdd(orow + c, g * (acc[i][j][r] + bias[j]));
                }
            }
        }
    }
}

extern "C" void kernel_launch(void* const* d_in, const int* in_sizes, int n_in,
                              void* d_out, int out_size, void* d_ws, size_t ws_size,
                              hipStream_t stream) {
    const float* x  = (const float*)d_in[0];
    const float* rw = (const float*)d_in[1];
    const float* w1 = (const float*)d_in[2];
    const float* b1 = (const float*)d_in[3];
    const float* w2 = (const float*)d_in[4];
    const float* b2 = (const float*)d_in[5];
    float* out = (float*)d_out;

    char* ws = (char*)d_ws;
    int*   counts  = (int*)ws;
    int*   offsets = (int*)(ws + 64);
    int*   btok    = (int*)(ws + 4096);
    float* bgate   = (float*)(ws + 4096 + 131072);

    hipMemsetAsync(d_out, 0, (size_t)out_size * sizeof(float), stream);
    hipMemsetAsync(counts, 0, 64, stream);

    const bool fast = ws_size >= ((size_t)137 << 20);

    if (fast) {
        unsigned short* xb = (unsigned short*)(ws + ((size_t)1 << 20));
        unsigned short* Wb = (unsigned short*)(ws + ((size_t)9 << 20));    // 64 MiB shared W1b/W2b
        unsigned short* H  = (unsigned short*)(ws + ((size_t)73 << 20));   // 64 MiB

        cast_kernel<<<(TTOK * CDIM) / (256 * 4), 256, 0, stream>>>(x, xb);
        router_kernel<<<TTOK / 4, 256, 0, stream>>>(x, rw, counts, btok, bgate);
        offsets_kernel<<<1, 64, 0, stream>>>(counts, offsets);
        cast_kernel<<<(NEXP * FFDIM * CDIM) / (256 * 4), 256, 0, stream>>>(w1, Wb);
        gemm1p_kernel<<<dim3(16, 16, NEXP), 512, 0, stream>>>(
            xb, Wb, b1, counts, offsets, btok, H);
        cast_kernel<<<(NEXP * CDIM * FFDIM) / (256 * 4), 256, 0, stream>>>(w2, Wb);
        gemm2p_kernel<<<dim3(4, 32, NEXP), 512, 0, stream>>>(
            H, Wb, b2, counts, offsets, btok, bgate, out);
    } else {
        unsigned short* xb = (unsigned short*)(ws + ((size_t)1 << 20));
        unsigned short* H  = (unsigned short*)(ws + ((size_t)16 << 20));

        cast_kernel<<<(TTOK * CDIM) / (256 * 4), 256, 0, stream>>>(x, xb);
        router_kernel<<<TTOK / 4, 256, 0, stream>>>(x, rw, counts, btok, bgate);
        offsets_kernel<<<1, 64, 0, stream>>>(counts, offsets);
        gemm1_kernel<<<dim3(FFDIM / 128, TTOK / 128, NEXP), 256, 0, stream>>>(
            xb, w1, b1, counts, offsets, btok, H);
        gemm2_kernel<<<dim3(CDIM / 128, TTOK / 128, NEXP), 256, 0, stream>>>(
            H, w2, b2, counts, offsets, btok, bgate, out);
    }
}

// Round 5
// 691.543 us; speedup vs baseline: 1.0897x; 1.0897x over previous
//
#include <hip/hip_runtime.h>
#include <hip/hip_bf16.h>
#include <cstdint>

// Problem constants (B=2, N=2048 -> T=4096 tokens)
#define TTOK  4096
#define CDIM  1024
#define FFDIM 4096
#define NEXP  8

// Fast-path workspace layout (needs >= 137 MiB):
//   [0,64)            counts[8]   (memset 0 each launch)
//   [64, ..)          offsets[9]
//   [4K, 4K+128K)     btok[8][4096]
//   [132K, 132K+128K) bgate[8][4096]
//   [1MB, 9MB)        xb : x as bf16 [4096,1024]
//   [9MB, 73MB)       Wb : bf16 weights, shared between passes (W1 then W2), 64 MiB
//   [73MB, 137MB)     H  : gelu(X W1^T + b1) bf16, compacted [8192, 4096], 64 MiB

typedef short short8 __attribute__((ext_vector_type(8)));   // 8 bf16 in 4 VGPRs
typedef float f32x4 __attribute__((ext_vector_type(4)));

__device__ __forceinline__ unsigned short f2bf(float f) {
    unsigned int u = __float_as_uint(f);
    u = u + 0x7fffu + ((u >> 16) & 1u);   // round-to-nearest-even
    return (unsigned short)(u >> 16);
}

// async global -> LDS, 16 bytes per lane. LDS dest MUST be wave-uniform base + lane*16.
__device__ __forceinline__ void gl_lds16(const unsigned short* g, unsigned short* l) {
    __builtin_amdgcn_global_load_lds(
        (const __attribute__((address_space(1))) unsigned int*)g,
        (__attribute__((address_space(3))) unsigned int*)l, 16, 0, 0);
}

// Row-pair-interleaved swizzled LDS offset (elements) for a [128][32] bf16 tile
// (viewed as 64 lines x 128B).  Element (row, k=kq*8..) lives at line=row>>1,
// chunk cp = (((row&1)<<2)|kq) ^ (line&7).  Frag-read pattern (16 lanes, rows
// r..r+15, fixed kq) then touches each of the 8 chunk positions exactly twice
// -> 2-way bank aliasing = free (m136).  Staging writes LDS linearly
// (global_load_lds requirement) with the inverse permutation applied to the
// per-lane GLOBAL source address (both-sides-or-neither rule).
// HW-verified correct + 0 bank conflicts in rounds 1/4.
__device__ __forceinline__ int swz_off(int row, int kq) {
    const int line = row >> 1;
    const int cp = ((((row & 1) << 2) | kq) ^ (line & 7));
    return line * 64 + cp * 8;
}

// ---------------- fp32 -> bf16 cast (x and weights) ----------------
__global__ void cast_kernel(const float* __restrict__ src, unsigned short* __restrict__ dst) {
    int i = blockIdx.x * blockDim.x + threadIdx.x;   // n/4 threads, exact division
    float4 v = reinterpret_cast<const float4*>(src)[i];
    ushort4 o;
    o.x = f2bf(v.x); o.y = f2bf(v.y); o.z = f2bf(v.z); o.w = f2bf(v.w);
    reinterpret_cast<ushort4*>(dst)[i] = o;
}

// ---------------- router: logits -> softmax -> top2 -> bucket scatter ----------------
__global__ void router_kernel(const float* __restrict__ x, const float* __restrict__ rw,
                              int* __restrict__ counts, int* __restrict__ btok,
                              float* __restrict__ bgate) {
    const int wave = threadIdx.x >> 6;
    const int lane = threadIdx.x & 63;
    const int t = blockIdx.x * 4 + wave;
    const float* xr = x + (size_t)t * CDIM;

    float acc[NEXP];
#pragma unroll
    for (int e = 0; e < NEXP; e++) acc[e] = 0.f;
    for (int c = lane; c < CDIM; c += 64) {
        float xv = xr[c];
#pragma unroll
        for (int e = 0; e < NEXP; e++) acc[e] += xv * rw[e * CDIM + c];
    }
#pragma unroll
    for (int e = 0; e < NEXP; e++) {
#pragma unroll
        for (int off = 32; off > 0; off >>= 1) acc[e] += __shfl_down(acc[e], off, 64);
    }
    if (lane == 0) {
        float mx = acc[0];
#pragma unroll
        for (int e = 1; e < NEXP; e++) mx = fmaxf(mx, acc[e]);
        float p[NEXP]; float s = 0.f;
#pragma unroll
        for (int e = 0; e < NEXP; e++) { p[e] = expf(acc[e] - mx); s += p[e]; }
        int i0 = 0;
#pragma unroll
        for (int e = 1; e < NEXP; e++) if (p[e] > p[i0]) i0 = e;
        int i1 = (i0 == 0) ? 1 : 0;
#pragma unroll
        for (int e = 0; e < NEXP; e++) if (e != i0 && p[e] > p[i1]) i1 = e;
        float pr0 = p[i0] / s, pr1 = p[i1] / s;
        float rs = 1.f / (pr0 + pr1 + 1e-9f);
        float w0 = pr0 * rs, w1 = pr1 * rs;
        int pos = atomicAdd(&counts[i0], 1);
        btok[i0 * TTOK + pos] = t; bgate[i0 * TTOK + pos] = w0;
        pos = atomicAdd(&counts[i1], 1);
        btok[i1 * TTOK + pos] = t; bgate[i1 * TTOK + pos] = w1;
    }
}

__global__ void offsets_kernel(const int* __restrict__ counts, int* __restrict__ offsets) {
    if (threadIdx.x == 0 && blockIdx.x == 0) {
        int s = 0;
        for (int e = 0; e < NEXP; e++) { offsets[e] = s; s += counts[e]; }
        offsets[NEXP] = s;
    }
}

// ===== FAST PATH (m97 structure + conflict-free swizzle) =====
// 128x128 tile, BK=32, double-buffered 32KB LDS -> ~5 blocks/CU: TLP hides the
// barrier drain (m114 implicit overlap).  LDS swizzled both-sides via swz_off:
// staging pre-swizzles the GLOBAL source per lane, gl_lds writes linearly,
// frag reads use swz_off -> 2-way aliasing only (round-0's 9.9M conflicts -> 0).

// pass A: H = gelu(X W1b^T + b1), 128x128 tile, BK=32
__global__ __launch_bounds__(256) void gemm1f_kernel(
    const unsigned short* __restrict__ xb, const unsigned short* __restrict__ w1b,
    const float* __restrict__ b1, const int* __restrict__ counts,
    const int* __restrict__ offsets, const int* __restrict__ btok,
    unsigned short* __restrict__ H) {
    const int e = blockIdx.z;
    const int cnt = counts[e];
    const int m0 = blockIdx.y * 128;
    if (m0 >= cnt) return;
    const int n0 = blockIdx.x * 128;   // FF columns
    const int po = offsets[e];

    __shared__ uint4 smem4[2048];      // 32 KB (two 16 KB buffers)
    unsigned short* smem = (unsigned short*)smem4;

    const int tid = threadIdx.x;
    const int wave = tid >> 6, lane = tid & 63;
    const int wm = (wave >> 1) << 6, wn = (wave & 1) << 6;
    const int lm = lane & 15, kq = lane >> 4;

    // ---- staging: pre-swizzled per-lane global sources ----
    // 256 threads cover one 4KB half-tile per call: line = tid>>3 (0..31),
    // deposited chunk = tid&7; inverse-swizzle gives the source (row, k).
    const int sline = tid >> 3;
    const int c128s = (tid & 7) ^ (sline & 7);
    const int prty  = c128s >> 2;
    const int skc   = (c128s & 3) << 3;
    const int arow0 = (sline << 1) + prty;     // 0..63
    const int tA0 = btok[e * TTOK + min(m0 + arow0, cnt - 1)];
    const int tA1 = btok[e * TTOK + min(m0 + 64 + arow0, cnt - 1)];
    const unsigned short* ga0 = xb + (size_t)tA0 * CDIM + skc;
    const unsigned short* ga1 = xb + (size_t)tA1 * CDIM + skc;
    const unsigned short* gb0 = w1b + ((size_t)e * FFDIM + n0 + arow0) * CDIM + skc;
    const unsigned short* gb1 = gb0 + (size_t)64 * CDIM;

    // ---- swizzled fragment offsets (within a 4096-element operand buffer) ----
    int offA[4], offB[4];
#pragma unroll
    for (int i = 0; i < 4; i++) offA[i] = swz_off(wm + i * 16 + lm, kq);
#pragma unroll
    for (int j = 0; j < 4; j++) offB[j] = swz_off(wn + j * 16 + lm, kq);

    f32x4 acc[4][4];
#pragma unroll
    for (int i = 0; i < 4; i++)
#pragma unroll
        for (int j = 0; j < 4; j++) { f32x4 z = {0.f, 0.f, 0.f, 0.f}; acc[i][j] = z; }

    // prologue: issue buf0 loads
    {
        unsigned short* base = smem;            // buf 0
        gl_lds16(ga0, base + tid * 8);
        gl_lds16(ga1, base + (256 + tid) * 8);
        gl_lds16(gb0, base + 4096 + tid * 8);
        gl_lds16(gb1, base + 4096 + (256 + tid) * 8);
    }

    for (int k0 = 0; k0 < CDIM; k0 += 32) {
        const int cur = (k0 >> 5) & 1;
        __syncthreads();                        // waits cur's loads (issued last iter)
        if (k0 + 32 < CDIM) {                   // prefetch next tile into other buffer
            unsigned short* base = smem + (cur ^ 1) * 8192;
            gl_lds16(ga0 + k0 + 32, base + tid * 8);
            gl_lds16(ga1 + k0 + 32, base + (256 + tid) * 8);
            gl_lds16(gb0 + k0 + 32, base + 4096 + tid * 8);
            gl_lds16(gb1 + k0 + 32, base + 4096 + (256 + tid) * 8);
        }
        const unsigned short* As = smem + cur * 8192;
        const unsigned short* Bs = As + 4096;
        short8 af[4], bfr[4];
#pragma unroll
        for (int i = 0; i < 4; i++) af[i] = *reinterpret_cast<const short8*>(&As[offA[i]]);
#pragma unroll
        for (int j = 0; j < 4; j++) bfr[j] = *reinterpret_cast<const short8*>(&Bs[offB[j]]);
#pragma unroll
        for (int i = 0; i < 4; i++)
#pragma unroll
            for (int j = 0; j < 4; j++)
                acc[i][j] = __builtin_amdgcn_mfma_f32_16x16x32_bf16(af[i], bfr[j], acc[i][j], 0, 0, 0);
    }
    __syncthreads();   // K-loop buffers dead; reuse first 16 KB as repack buffer

    float bias[4];
#pragma unroll
    for (int j = 0; j < 4; j++) bias[j] = b1[e * FFDIM + n0 + wn + j * 16 + lm];

    unsigned short* Cs = smem;   // 64 x 128 bf16 = 16 KB
#pragma unroll
    for (int p = 0; p < 2; p++) {
        if ((wave >> 1) == p) {
#pragma unroll
            for (int i = 0; i < 4; i++) {
#pragma unroll
                for (int r = 0; r < 4; r++) {
                    const int row = i * 16 + kq * 4 + r;   // 0..63 relative to p*64
#pragma unroll
                    for (int j = 0; j < 4; j++) {
                        float h = acc[i][j][r] + bias[j];
                        float g = 0.5f * h * (1.f + erff(h * 0.70710678118654752f));
                        Cs[row * 128 + wn + j * 16 + lm] = f2bf(g);
                    }
                }
            }
        }
        __syncthreads();
#pragma unroll
        for (int q = 0; q < 4; q++) {
            const int c = q * 256 + tid;
            const int row = c >> 4;
            const int col8 = (c & 15) << 3;
            const int mrow = m0 + p * 64 + row;
            if (mrow < cnt)
                *reinterpret_cast<uint4*>(&H[(size_t)(po + mrow) * FFDIM + n0 + col8]) =
                    *reinterpret_cast<const uint4*>(&Cs[row * 128 + col8]);
        }
        __syncthreads();
    }
}

// pass B: out += gate * (H W2b^T + b2), split-K=2, atomic scatter epilogue
__global__ __launch_bounds__(256) void gemm2f_kernel(
    const unsigned short* __restrict__ H, const unsigned short* __restrict__ w2b,
    const float* __restrict__ b2, const int* __restrict__ counts,
    const int* __restrict__ offsets, const int* __restrict__ btok,
    const float* __restrict__ bgate, float* __restrict__ out) {
    const int e = blockIdx.z;
    const int cnt = counts[e];
    const int m0 = (blockIdx.y >> 1) * 128;
    const int ks = blockIdx.y & 1;             // K split: [ks*2048, ks*2048+2048)
    if (m0 >= cnt) return;
    const int n0 = blockIdx.x * 128;           // C columns
    const int po = offsets[e];

    __shared__ uint4 smem4[2048];              // 32 KB
    unsigned short* smem = (unsigned short*)smem4;

    const int tid = threadIdx.x;
    const int wave = tid >> 6, lane = tid & 63;
    const int wm = (wave >> 1) << 6, wn = (wave & 1) << 6;
    const int lm = lane & 15, kq = lane >> 4;

    const int sline = tid >> 3;
    const int c128s = (tid & 7) ^ (sline & 7);
    const int prty  = c128s >> 2;
    const int skc   = (c128s & 3) << 3;
    const int arow0 = (sline << 1) + prty;     // 0..63
    const int koff  = ks * 2048;
    const int r0 = min(m0 + arow0, cnt - 1);
    const int r1 = min(m0 + 64 + arow0, cnt - 1);
    const unsigned short* ga0 = H + (size_t)(po + r0) * FFDIM + koff + skc;
    const unsigned short* ga1 = H + (size_t)(po + r1) * FFDIM + koff + skc;
    const unsigned short* gb0 = w2b + ((size_t)e * CDIM + n0 + arow0) * FFDIM + koff + skc;
    const unsigned short* gb1 = gb0 + (size_t)64 * FFDIM;

    int offA[4], offB[4];
#pragma unroll
    for (int i = 0; i < 4; i++) offA[i] = swz_off(wm + i * 16 + lm, kq);
#pragma unroll
    for (int j = 0; j < 4; j++) offB[j] = swz_off(wn + j * 16 + lm, kq);

    f32x4 acc[4][4];
#pragma unroll
    for (int i = 0; i < 4; i++)
#pragma unroll
        for (int j = 0; j < 4; j++) { f32x4 z = {0.f, 0.f, 0.f, 0.f}; acc[i][j] = z; }

    {
        unsigned short* base = smem;            // buf 0
        gl_lds16(ga0, base + tid * 8);
        gl_lds16(ga1, base + (256 + tid) * 8);
        gl_lds16(gb0, base + 4096 + tid * 8);
        gl_lds16(gb1, base + 4096 + (256 + tid) * 8);
    }

    for (int k0 = 0; k0 < 2048; k0 += 32) {
        const int cur = (k0 >> 5) & 1;
        __syncthreads();
        if (k0 + 32 < 2048) {
            unsigned short* base = smem + (cur ^ 1) * 8192;
            gl_lds16(ga0 + k0 + 32, base + tid * 8);
            gl_lds16(ga1 + k0 + 32, base + (256 + tid) * 8);
            gl_lds16(gb0 + k0 + 32, base + 4096 + tid * 8);
            gl_lds16(gb1 + k0 + 32, base + 4096 + (256 + tid) * 8);
        }
        const unsigned short* As = smem + cur * 8192;
        const unsigned short* Bs = As + 4096;
        short8 af[4], bfr[4];
#pragma unroll
        for (int i = 0; i < 4; i++) af[i] = *reinterpret_cast<const short8*>(&As[offA[i]]);
#pragma unroll
        for (int j = 0; j < 4; j++) bfr[j] = *reinterpret_cast<const short8*>(&Bs[offB[j]]);
#pragma unroll
        for (int i = 0; i < 4; i++)
#pragma unroll
            for (int j = 0; j < 4; j++)
                acc[i][j] = __builtin_amdgcn_mfma_f32_16x16x32_bf16(af[i], bfr[j], acc[i][j], 0, 0, 0);
    }

    float bias[4];
#pragma unroll
    for (int j = 0; j < 4; j++) bias[j] = (ks == 0) ? b2[e * CDIM + n0 + wn + j * 16 + lm] : 0.f;

#pragma unroll
    for (int i = 0; i < 4; i++) {
#pragma unroll
        for (int r = 0; r < 4; r++) {
            const int mrow = m0 + wm + i * 16 + kq * 4 + r;
            if (mrow < cnt) {
                const int tok = btok[e * TTOK + mrow];
                const float g = bgate[e * TTOK + mrow];
                float* orow = out + (size_t)tok * CDIM;
#pragma unroll
                for (int j = 0; j < 4; j++)
                    atomicAdd(orow + n0 + wn + j * 16 + lm, g * (acc[i][j][r] + bias[j]));
            }
        }
    }
}

// ================= SLOW FALLBACK (round-1 kernels, in-loop fp32->bf16) =================

__global__ __launch_bounds__(256) void gemm1_kernel(
    const unsigned short* __restrict__ xb, const float* __restrict__ w1,
    const float* __restrict__ b1, const int* __restrict__ counts,
    const int* __restrict__ offsets, const int* __restrict__ btok,
    unsigned short* __restrict__ H) {
    const int e = blockIdx.z;
    const int cnt = counts[e];
    const int m0 = blockIdx.y * 128;
    if (m0 >= cnt) return;
    const int n0 = blockIdx.x * 128;
    const int po = offsets[e];

    __shared__ unsigned short As[128][32];
    __shared__ unsigned short Bs[128][32];

    const int tid = threadIdx.x;
    const int wave = tid >> 6, lane = tid & 63;
    const int wm = (wave >> 1) << 6, wn = (wave & 1) << 6;
    const int lm = lane & 15, kq = lane >> 4;

    f32x4 acc[4][4];
#pragma unroll
    for (int i = 0; i < 4; i++)
#pragma unroll
        for (int j = 0; j < 4; j++) { f32x4 z = {0.f, 0.f, 0.f, 0.f}; acc[i][j] = z; }

    const float* w1e = w1 + (size_t)e * FFDIM * CDIM;
    const int arow = tid >> 1;
    const int acolb = (tid & 1) * 16;
    int tokA = -1;
    if (m0 + arow < cnt) tokA = btok[e * TTOK + m0 + arow];
    const int brow = tid >> 1;
    const int bcol = (tid & 1) * 16;

    for (int k0 = 0; k0 < CDIM; k0 += 32) {
        uint4 a0 = {0, 0, 0, 0}, a1 = {0, 0, 0, 0};
        if (tokA >= 0) {
            const uint4* src = reinterpret_cast<const uint4*>(xb + (size_t)tokA * CDIM + k0 + acolb);
            a0 = src[0]; a1 = src[1];
        }
        *reinterpret_cast<uint4*>(&As[arow][acolb]) = a0;
        *reinterpret_cast<uint4*>(&As[arow][acolb + 8]) = a1;
        {
            const float* src = w1e + (size_t)(n0 + brow) * CDIM + k0 + bcol;
            ushort4* dst = reinterpret_cast<ushort4*>(&Bs[brow][bcol]);
#pragma unroll
            for (int q = 0; q < 4; q++) {
                float4 v = reinterpret_cast<const float4*>(src)[q];
                ushort4 o; o.x = f2bf(v.x); o.y = f2bf(v.y); o.z = f2bf(v.z); o.w = f2bf(v.w);
                dst[q] = o;
            }
        }
        __syncthreads();
        short8 af[4], bfr[4];
#pragma unroll
        for (int i = 0; i < 4; i++) af[i] = *reinterpret_cast<const short8*>(&As[wm + i * 16 + lm][kq * 8]);
#pragma unroll
        for (int j = 0; j < 4; j++) bfr[j] = *reinterpret_cast<const short8*>(&Bs[wn + j * 16 + lm][kq * 8]);
#pragma unroll
        for (int i = 0; i < 4; i++)
#pragma unroll
            for (int j = 0; j < 4; j++)
                acc[i][j] = __builtin_amdgcn_mfma_f32_16x16x32_bf16(af[i], bfr[j], acc[i][j], 0, 0, 0);
        __syncthreads();
    }

#pragma unroll
    for (int j = 0; j < 4; j++) {
        const int fcol = n0 + wn + j * 16 + lm;
        const float bias = b1[e * FFDIM + fcol];
#pragma unroll
        for (int i = 0; i < 4; i++) {
#pragma unroll
            for (int r = 0; r < 4; r++) {
                const int mrow = m0 + wm + i * 16 + kq * 4 + r;
                if (mrow < cnt) {
                    float h = acc[i][j][r] + bias;
                    float g = 0.5f * h * (1.f + erff(h * 0.70710678118654752f));
                    H[(size_t)(po + mrow) * FFDIM + fcol] = f2bf(g);
                }
            }
        }
    }
}

__global__ __launch_bounds__(256) void gemm2_kernel(
    const unsigned short* __restrict__ H, const float* __restrict__ w2,
    const float* __restrict__ b2, const int* __restrict__ counts,
    const int* __restrict__ offsets, const int* __restrict__ btok,
    const float* __restrict__ bgate, float* __restrict__ out) {
    const int e = blockIdx.z;
    const int cnt = counts[e];
    const int m0 = blockIdx.y * 128;
    if (m0 >= cnt) return;
    const int n0 = blockIdx.x * 128;
    const int po = offsets[e];

    __shared__ unsigned short As[128][32];
    __shared__ unsigned short Bs[128][32];

    const int tid = threadIdx.x;
    const int wave = tid >> 6, lane = tid & 63;
    const int wm = (wave >> 1) << 6, wn = (wave & 1) << 6;
    const int lm = lane & 15, kq = lane >> 4;

    f32x4 acc[4][4];
#pragma unroll
    for (int i = 0; i < 4; i++)
#pragma unroll
        for (int j = 0; j < 4; j++) { f32x4 z = {0.f, 0.f, 0.f, 0.f}; acc[i][j] = z; }

    const float* w2e = w2 + (size_t)e * CDIM * FFDIM;
    const int arow = tid >> 1;
    const int acolb = (tid & 1) * 16;
    const bool aval = (m0 + arow < cnt);
    const unsigned short* asrc = H + (size_t)(po + m0 + arow) * FFDIM + acolb;
    const int brow = tid >> 1;
    const int bcol = (tid & 1) * 16;

    for (int k0 = 0; k0 < FFDIM; k0 += 32) {
        uint4 a0 = {0, 0, 0, 0}, a1 = {0, 0, 0, 0};
        if (aval) {
            const uint4* src = reinterpret_cast<const uint4*>(asrc + k0);
            a0 = src[0]; a1 = src[1];
        }
        *reinterpret_cast<uint4*>(&As[arow][acolb]) = a0;
        *reinterpret_cast<uint4*>(&As[arow][acolb + 8]) = a1;
        {
            const float* src = w2e + (size_t)(n0 + brow) * FFDIM + k0 + bcol;
            ushort4* dst = reinterpret_cast<ushort4*>(&Bs[brow][bcol]);
#pragma unroll
            for (int q = 0; q < 4; q++) {
                float4 v = reinterpret_cast<const float4*>(src)[q];
                ushort4 o; o.x = f2bf(v.x); o.y = f2bf(v.y); o.z = f2bf(v.z); o.w = f2bf(v.w);
                dst[q] = o;
            }
        }
        __syncthreads();
        short8 af[4], bfr[4];
#pragma unroll
        for (int i = 0; i < 4; i++) af[i] = *reinterpret_cast<const short8*>(&As[wm + i * 16 + lm][kq * 8]);
#pragma unroll
        for (int j = 0; j < 4; j++) bfr[j] = *reinterpret_cast<const short8*>(&Bs[wn + j * 16 + lm][kq * 8]);
#pragma unroll
        for (int i = 0; i < 4; i++)
#pragma unroll
            for (int j = 0; j < 4; j++)
                acc[i][j] = __builtin_amdgcn_mfma_f32_16x16x32_bf16(af[i], bfr[j], acc[i][j], 0, 0, 0);
        __syncthreads();
    }

    float bias[4];
#pragma unroll
    for (int j = 0; j < 4; j++) bias[j] = b2[e * CDIM + n0 + wn + j * 16 + lm];

#pragma unroll
    for (int i = 0; i < 4; i++) {
#pragma unroll
        for (int r = 0; r < 4; r++) {
            const int mrow = m0 + wm + i * 16 + kq * 4 + r;
            if (mrow < cnt) {
                const int tok = btok[e * TTOK + mrow];
                const float g = bgate[e * TTOK + mrow];
                float* orow = out + (size_t)tok * CDIM;
#pragma unroll
                for (int j = 0; j < 4; j++) {
                    const int c = n0 + wn + j * 16 + lm;
                    atomicAdd(orow + c, g * (acc[i][j][r] + bias[j]));
                }
            }
        }
    }
}

extern "C" void kernel_launch(void* const* d_in, const int* in_sizes, int n_in,
                              void* d_out, int out_size, void* d_ws, size_t ws_size,
                              hipStream_t stream) {
    const float* x  = (const float*)d_in[0];
    const float* rw = (const float*)d_in[1];
    const float* w1 = (const float*)d_in[2];
    const float* b1 = (const float*)d_in[3];
    const float* w2 = (const float*)d_in[4];
    const float* b2 = (const float*)d_in[5];
    float* out = (float*)d_out;

    char* ws = (char*)d_ws;
    int*   counts  = (int*)ws;
    int*   offsets = (int*)(ws + 64);
    int*   btok    = (int*)(ws + 4096);
    float* bgate   = (float*)(ws + 4096 + 131072);

    hipMemsetAsync(d_out, 0, (size_t)out_size * sizeof(float), stream);
    hipMemsetAsync(counts, 0, 64, stream);

    const bool fast = ws_size >= ((size_t)137 << 20);

    if (fast) {
        unsigned short* xb = (unsigned short*)(ws + ((size_t)1 << 20));
        unsigned short* Wb = (unsigned short*)(ws + ((size_t)9 << 20));    // 64 MiB shared W1b/W2b
        unsigned short* H  = (unsigned short*)(ws + ((size_t)73 << 20));   // 64 MiB

        cast_kernel<<<(TTOK * CDIM) / (256 * 4), 256, 0, stream>>>(x, xb);
        router_kernel<<<TTOK / 4, 256, 0, stream>>>(x, rw, counts, btok, bgate);
        offsets_kernel<<<1, 64, 0, stream>>>(counts, offsets);
        cast_kernel<<<(NEXP * FFDIM * CDIM) / (256 * 4), 256, 0, stream>>>(w1, Wb);
        gemm1f_kernel<<<dim3(FFDIM / 128, TTOK / 128, NEXP), 256, 0, stream>>>(
            xb, Wb, b1, counts, offsets, btok, H);
        cast_kernel<<<(NEXP * CDIM * FFDIM) / (256 * 4), 256, 0, stream>>>(w2, Wb);
        gemm2f_kernel<<<dim3(CDIM / 128, (TTOK / 128) * 2, NEXP), 256, 0, stream>>>(
            H, Wb, b2, counts, offsets, btok, bgate, out);
    } else {
        unsigned short* xb = (unsigned short*)(ws + ((size_t)1 << 20));
        unsigned short* H  = (unsigned short*)(ws + ((size_t)16 << 20));

        cast_kernel<<<(TTOK * CDIM) / (256 * 4), 256, 0, stream>>>(x, xb);
        router_kernel<<<TTOK / 4, 256, 0, stream>>>(x, rw, counts, btok, bgate);
        offsets_kernel<<<1, 64, 0, stream>>>(counts, offsets);
        gemm1_kernel<<<dim3(FFDIM / 128, TTOK / 128, NEXP), 256, 0, stream>>>(
            xb, w1, b1, counts, offsets, btok, H);
        gemm2_kernel<<<dim3(CDIM / 128, TTOK / 128, NEXP), 256, 0, stream>>>(
            H, w2, b2, counts, offsets, btok, bgate, out);
    }
}

// Round 7
// 688.422 us; speedup vs baseline: 1.0946x; 1.0045x over previous
//
#include <hip/hip_runtime.h>
#include <hip/hip_bf16.h>
#include <cstdint>

// Problem constants (B=2, N=2048 -> T=4096 tokens)
#define TTOK  4096
#define CDIM  1024
#define FFDIM 4096
#define NEXP  8

// Fast-path workspace layout (needs >= 137 MiB):
//   [0,64)            counts[8]   (memset 0 each launch)
//   [64, ..)          offsets[9]
//   [4K, 4K+128K)     btok[8][4096]
//   [132K, 132K+128K) bgate[8][4096]
//   [1MB, 9MB)        xb : x as bf16 [4096,1024]
//   [9MB, 73MB)       Wb : bf16 weights, shared between passes (W1 then W2), 64 MiB
//   [73MB, 137MB)     H  : gelu(X W1^T + b1) bf16, compacted [8192, 4096], 64 MiB

typedef short short8 __attribute__((ext_vector_type(8)));   // 8 bf16 in 4 VGPRs
typedef float f32x4 __attribute__((ext_vector_type(4)));

__device__ __forceinline__ unsigned short f2bf(float f) {
    unsigned int u = __float_as_uint(f);
    u = u + 0x7fffu + ((u >> 16) & 1u);   // round-to-nearest-even
    return (unsigned short)(u >> 16);
}

// async global -> LDS, 16 bytes per lane. LDS dest MUST be wave-uniform base + lane*16.
__device__ __forceinline__ void gl_lds16(const unsigned short* g, unsigned short* l) {
    __builtin_amdgcn_global_load_lds(
        (const __attribute__((address_space(1))) unsigned int*)g,
        (__attribute__((address_space(3))) unsigned int*)l, 16, 0, 0);
}

// Row-pair-interleaved swizzled LDS offset (elements) for a [R][32] bf16 region
// (R<=256), 128B lines = row pairs.  Element (row, k=kq*8..) lives at
// line=row>>1, chunk cp = (((row&1)<<2)|kq) ^ (line&7).  MFMA frag read
// (16 lanes, rows r..r+15, fixed kq) touches each chunk slot exactly twice
// -> 2-way bank aliasing = free.  Staging writes LDS linearly (global_load_lds
// requirement) with the inverse permutation on the per-lane GLOBAL source.
// HW-verified (correctness + 0 bank conflicts) in rounds 1/4/5.
__device__ __forceinline__ int swz_off(int row, int kq) {
    const int line = row >> 1;
    const int cp = ((((row & 1) << 2) | kq) ^ (line & 7));
    return line * 64 + cp * 8;
}

#define SBAR() do { __builtin_amdgcn_sched_barrier(0); \
                    __builtin_amdgcn_s_barrier();      \
                    __builtin_amdgcn_sched_barrier(0); } while (0)
#define LGKM0() do { asm volatile("s_waitcnt lgkmcnt(0)" ::: "memory"); \
                     __builtin_amdgcn_sched_barrier(0); } while (0)

// ---------------- fp32 -> bf16 cast (x and weights) ----------------
__global__ void cast_kernel(const float* __restrict__ src, unsigned short* __restrict__ dst) {
    int i = blockIdx.x * blockDim.x + threadIdx.x;   // n/4 threads, exact division
    float4 v = reinterpret_cast<const float4*>(src)[i];
    ushort4 o;
    o.x = f2bf(v.x); o.y = f2bf(v.y); o.z = f2bf(v.z); o.w = f2bf(v.w);
    reinterpret_cast<ushort4*>(dst)[i] = o;
}

// ---------------- router: logits -> softmax -> top2 -> bucket scatter ----------------
__global__ void router_kernel(const float* __restrict__ x, const float* __restrict__ rw,
                              int* __restrict__ counts, int* __restrict__ btok,
                              float* __restrict__ bgate) {
    const int wave = threadIdx.x >> 6;
    const int lane = threadIdx.x & 63;
    const int t = blockIdx.x * 4 + wave;
    const float* xr = x + (size_t)t * CDIM;

    float acc[NEXP];
#pragma unroll
    for (int e = 0; e < NEXP; e++) acc[e] = 0.f;
    for (int c = lane; c < CDIM; c += 64) {
        float xv = xr[c];
#pragma unroll
        for (int e = 0; e < NEXP; e++) acc[e] += xv * rw[e * CDIM + c];
    }
#pragma unroll
    for (int e = 0; e < NEXP; e++) {
#pragma unroll
        for (int off = 32; off > 0; off >>= 1) acc[e] += __shfl_down(acc[e], off, 64);
    }
    if (lane == 0) {
        float mx = acc[0];
#pragma unroll
        for (int e = 1; e < NEXP; e++) mx = fmaxf(mx, acc[e]);
        float p[NEXP]; float s = 0.f;
#pragma unroll
        for (int e = 0; e < NEXP; e++) { p[e] = expf(acc[e] - mx); s += p[e]; }
        int i0 = 0;
#pragma unroll
        for (int e = 1; e < NEXP; e++) if (p[e] > p[i0]) i0 = e;
        int i1 = (i0 == 0) ? 1 : 0;
#pragma unroll
        for (int e = 0; e < NEXP; e++) if (e != i0 && p[e] > p[i1]) i1 = e;
        float pr0 = p[i0] / s, pr1 = p[i1] / s;
        float rs = 1.f / (pr0 + pr1 + 1e-9f);
        float w0 = pr0 * rs, w1 = pr1 * rs;
        int pos = atomicAdd(&counts[i0], 1);
        btok[i0 * TTOK + pos] = t; bgate[i0 * TTOK + pos] = w0;
        pos = atomicAdd(&counts[i1], 1);
        btok[i1 * TTOK + pos] = t; bgate[i1 * TTOK + pos] = w1;
    }
}

__global__ void offsets_kernel(const int* __restrict__ counts, int* __restrict__ offsets) {
    if (threadIdx.x == 0 && blockIdx.x == 0) {
        int s = 0;
        for (int e = 0; e < NEXP; e++) { offsets[e] = s; s += counts[e]; }
        offsets[NEXP] = s;
    }
}

// ===== FAST PATH: 256x256 8-phase counted-vmcnt template (m201/m248 port) =====
// BK=64; LDS 128 KB = 2 buffers x {Ak0,Ak1,Bk0,Bk1} 16 KB regions (k-half split).
// 512 thr = 8 waves (2m x 4n), per-wave output 128x64 (acc[8][4] f32x4).
// 4 fine phases per K-tile: {ds_read subtile | stage 1 half-region (2 gl_lds) |
// lgkmcnt(0) | setprio(1) 16 MFMA setprio(0) | [vmcnt(4)] barrier}.
// vmcnt(4) exactly at ends of phases 1 and 3 -- never 0 in the main loop.
// Ledger (loads FIFO, 2 per half-region): prologue issues Ak0,Bk0,Ak1,Bk1 (8);
// wait vmcnt(4) -> Ak0,Bk0 landed.  p0 stages next Ak0, p1 next Bk0 -> 8
// outstanding; vmcnt(4) at p1 end -> this tile's Ak1,Bk1 landed (read by p2/p3).
// p2 stages next Ak1, p3 next Bk1 -> 8 outstanding; vmcnt(4) at p3 end ->
// next tile's Ak0,Bk0 landed.  Steady.  Last tile stages wrapped dummies.

// pass A: H = gelu(X W1b^T + b1)
__global__ __launch_bounds__(512, 2) void gemm1p8_kernel(
    const unsigned short* __restrict__ xb, const unsigned short* __restrict__ w1b,
    const float* __restrict__ b1, const int* __restrict__ counts,
    const int* __restrict__ offsets, const int* __restrict__ btok,
    unsigned short* __restrict__ H) {
    const int e = blockIdx.z;
    const int cnt = counts[e];
    const int m0 = blockIdx.y * 256;
    if (m0 >= cnt) return;
    const int n0 = blockIdx.x * 256;   // FF columns
    const int po = offsets[e];
    const int NT = CDIM / 64;          // 16 K-tiles

    __shared__ uint4 smem4[8192];      // 128 KB
    unsigned short* S = (unsigned short*)smem4;

    const int tid = threadIdx.x;
    const int wid = tid >> 6, lane = tid & 63;
    const int lm = lane & 15, kq = lane >> 4;
    const int wr = wid >> 2, wc = wid & 3;

    // ---- staging sources (inverse-swizzled per-lane global addresses) ----
    const int sline = tid >> 3;                 // 0..63
    const int c128s = (tid & 7) ^ (sline & 7);
    const int prty  = c128s >> 2;
    const int skc   = (c128s & 3) << 3;
    const int rowLo = (sline << 1) + prty;      // 0..127
    const int tokLo = btok[e * TTOK + min(m0 + rowLo, cnt - 1)];
    const int tokHi = btok[e * TTOK + min(m0 + 128 + rowLo, cnt - 1)];
    const unsigned short* aLo = xb + (size_t)tokLo * CDIM + skc;
    const unsigned short* aHi = xb + (size_t)tokHi * CDIM + skc;
    const unsigned short* bLo = w1b + ((size_t)e * FFDIM + n0 + rowLo) * CDIM + skc;
    const unsigned short* bHi = bLo + (size_t)128 * CDIM;

    // ---- swizzled fragment offsets (within a 16 KB region, elements) ----
    int offA[8], offB[4];
#pragma unroll
    for (int f = 0; f < 8; f++) offA[f] = swz_off(wr * 128 + f * 16 + lm, kq);
#pragma unroll
    for (int g = 0; g < 4; g++) offB[g] = swz_off(wc * 64 + g * 16 + lm, kq);

    f32x4 acc[8][4];
#pragma unroll
    for (int f = 0; f < 8; f++)
#pragma unroll
        for (int g = 0; g < 4; g++) { f32x4 z = {0.f, 0.f, 0.f, 0.f}; acc[f][g] = z; }

    // ---- prologue: tile 0 -> buf0, order Ak0, Bk0, Ak1, Bk1 ----
    gl_lds16(aLo,      S + tid * 8);
    gl_lds16(aHi,      S + 4096 + tid * 8);
    gl_lds16(bLo,      S + 16384 + tid * 8);
    gl_lds16(bHi,      S + 16384 + 4096 + tid * 8);
    gl_lds16(aLo + 32, S + 8192 + tid * 8);
    gl_lds16(aHi + 32, S + 8192 + 4096 + tid * 8);
    gl_lds16(bLo + 32, S + 24576 + tid * 8);
    gl_lds16(bHi + 32, S + 24576 + 4096 + tid * 8);
    asm volatile("s_waitcnt vmcnt(4)" ::: "memory");   // Ak0,Bk0 landed
    SBAR();

    for (int t = 0; t < NT; ++t) {
        unsigned short* Cb = S + (t & 1) * 32768;
        unsigned short* Nb = S + ((t & 1) ^ 1) * 32768;
        const int ts = (t + 1 == NT) ? 0 : t + 1;      // wrap: dummy, keeps ledger uniform
        const int g0 = ts * 64;
        short8 bfr[4];
        // ---- phase 0: (m0..3, k-half0) ----
        {
            short8 af[4];
#pragma unroll
            for (int f = 0; f < 4; f++) af[f] = *reinterpret_cast<const short8*>(&Cb[offA[f]]);
#pragma unroll
            for (int g = 0; g < 4; g++) bfr[g] = *reinterpret_cast<const short8*>(&Cb[16384 + offB[g]]);
            gl_lds16(aLo + g0, Nb + tid * 8);
            gl_lds16(aHi + g0, Nb + 4096 + tid * 8);
            LGKM0();
            __builtin_amdgcn_s_setprio(1);
#pragma unroll
            for (int f = 0; f < 4; f++)
#pragma unroll
                for (int g = 0; g < 4; g++)
                    acc[f][g] = __builtin_amdgcn_mfma_f32_16x16x32_bf16(af[f], bfr[g], acc[f][g], 0, 0, 0);
            __builtin_amdgcn_s_setprio(0);
            SBAR();
        }
        // ---- phase 1: (m4..7, k-half0) ----
        {
            short8 af[4];
#pragma unroll
            for (int f = 0; f < 4; f++) af[f] = *reinterpret_cast<const short8*>(&Cb[offA[4 + f]]);
            gl_lds16(bLo + g0, Nb + 16384 + tid * 8);
            gl_lds16(bHi + g0, Nb + 16384 + 4096 + tid * 8);
            LGKM0();
            __builtin_amdgcn_s_setprio(1);
#pragma unroll
            for (int f = 0; f < 4; f++)
#pragma unroll
                for (int g = 0; g < 4; g++)
                    acc[4 + f][g] = __builtin_amdgcn_mfma_f32_16x16x32_bf16(af[f], bfr[g], acc[4 + f][g], 0, 0, 0);
            __builtin_amdgcn_s_setprio(0);
            asm volatile("s_waitcnt vmcnt(4)" ::: "memory");   // this tile's Ak1,Bk1 landed
            SBAR();
        }
        // ---- phase 2: (m0..3, k-half1) ----
        {
            short8 af[4];
#pragma unroll
            for (int f = 0; f < 4; f++) af[f] = *reinterpret_cast<const short8*>(&Cb[8192 + offA[f]]);
#pragma unroll
            for (int g = 0; g < 4; g++) bfr[g] = *reinterpret_cast<const short8*>(&Cb[24576 + offB[g]]);
            gl_lds16(aLo + g0 + 32, Nb + 8192 + tid * 8);
            gl_lds16(aHi + g0 + 32, Nb + 8192 + 4096 + tid * 8);
            LGKM0();
            __builtin_amdgcn_s_setprio(1);
#pragma unroll
            for (int f = 0; f < 4; f++)
#pragma unroll
                for (int g = 0; g < 4; g++)
                    acc[f][g] = __builtin_amdgcn_mfma_f32_16x16x32_bf16(af[f], bfr[g], acc[f][g], 0, 0, 0);
            __builtin_amdgcn_s_setprio(0);
            SBAR();
        }
        // ---- phase 3: (m4..7, k-half1) ----
        {
            short8 af[4];
#pragma unroll
            for (int f = 0; f < 4; f++) af[f] = *reinterpret_cast<const short8*>(&Cb[8192 + offA[4 + f]]);
            gl_lds16(bLo + g0 + 32, Nb + 24576 + tid * 8);
            gl_lds16(bHi + g0 + 32, Nb + 24576 + 4096 + tid * 8);
            LGKM0();
            __builtin_amdgcn_s_setprio(1);
#pragma unroll
            for (int f = 0; f < 4; f++)
#pragma unroll
                for (int g = 0; g < 4; g++)
                    acc[4 + f][g] = __builtin_amdgcn_mfma_f32_16x16x32_bf16(af[f], bfr[g], acc[4 + f][g], 0, 0, 0);
            __builtin_amdgcn_s_setprio(0);
            asm volatile("s_waitcnt vmcnt(4)" ::: "memory");   // next tile's Ak0,Bk0 landed
            SBAR();
        }
    }

    asm volatile("s_waitcnt vmcnt(0)" ::: "memory");   // drain wrapped dummies
    __syncthreads();                                   // LDS ring dead; reuse for repack

    // ---- epilogue (round-1-proven): bias + GELU + bf16, swizzled repack, coalesced store ----
    float bias[4];
#pragma unroll
    for (int g = 0; g < 4; g++) bias[g] = b1[e * FFDIM + n0 + wc * 64 + g * 16 + lm];

    unsigned short* Cs = S;   // 256x256 bf16 = 128 KB, chunk-XOR swizzled vs row
#pragma unroll
    for (int f = 0; f < 8; f++) {
#pragma unroll
        for (int r = 0; r < 4; r++) {
            const int row = wr * 128 + f * 16 + kq * 4 + r;
#pragma unroll
            for (int g = 0; g < 4; g++) {
                const int col = wc * 64 + g * 16 + lm;
                float h = acc[f][g][r] + bias[g];
                float gl = 0.5f * h * (1.f + erff(h * 0.70710678118654752f));
                Cs[(row * 256 + col) ^ ((row & 7) << 3)] = f2bf(gl);
            }
        }
    }
    __syncthreads();
#pragma unroll
    for (int q = 0; q < 16; q++) {
        const int cq = q * 512 + tid;
        const int row = cq >> 5;
        const int cc = cq & 31;
        const int mrow = m0 + row;
        if (mrow < cnt)
            *reinterpret_cast<uint4*>(&H[(size_t)(po + mrow) * FFDIM + n0 + cc * 8]) =
                *reinterpret_cast<const uint4*>(&Cs[(row * 256 + cc * 8) ^ ((row & 7) << 3)]);
    }
}

// pass B: out += gate * (H W2b^T + b2), split-K=2, atomic scatter epilogue
__global__ __launch_bounds__(512, 2) void gemm2p8_kernel(
    const unsigned short* __restrict__ H, const unsigned short* __restrict__ w2b,
    const float* __restrict__ b2, const int* __restrict__ counts,
    const int* __restrict__ offsets, const int* __restrict__ btok,
    const float* __restrict__ bgate, float* __restrict__ out) {
    const int e = blockIdx.z;
    const int cnt = counts[e];
    const int m0 = (blockIdx.y >> 1) * 256;
    const int ks = blockIdx.y & 1;             // K split: [ks*2048, ks*2048+2048)
    if (m0 >= cnt) return;
    const int n0 = blockIdx.x * 256;           // C columns
    const int po = offsets[e];
    const int NT = 2048 / 64;                  // 32 K-tiles

    __shared__ uint4 smem4[8192];              // 128 KB
    unsigned short* S = (unsigned short*)smem4;

    const int tid = threadIdx.x;
    const int wid = tid >> 6, lane = tid & 63;
    const int lm = lane & 15, kq = lane >> 4;
    const int wr = wid >> 2, wc = wid & 3;

    const int sline = tid >> 3;
    const int c128s = (tid & 7) ^ (sline & 7);
    const int prty  = c128s >> 2;
    const int skc   = (c128s & 3) << 3;
    const int rowLo = (sline << 1) + prty;     // 0..127
    const int koff  = ks * 2048;
    const int rLo = min(m0 + rowLo, cnt - 1);
    const int rHi = min(m0 + 128 + rowLo, cnt - 1);
    const unsigned short* aLo = H + (size_t)(po + rLo) * FFDIM + koff + skc;
    const unsigned short* aHi = H + (size_t)(po + rHi) * FFDIM + koff + skc;
    const unsigned short* bLo = w2b + ((size_t)e * CDIM + n0 + rowLo) * FFDIM + koff + skc;
    const unsigned short* bHi = bLo + (size_t)128 * FFDIM;

    int offA[8], offB[4];
#pragma unroll
    for (int f = 0; f < 8; f++) offA[f] = swz_off(wr * 128 + f * 16 + lm, kq);
#pragma unroll
    for (int g = 0; g < 4; g++) offB[g] = swz_off(wc * 64 + g * 16 + lm, kq);

    f32x4 acc[8][4];
#pragma unroll
    for (int f = 0; f < 8; f++)
#pragma unroll
        for (int g = 0; g < 4; g++) { f32x4 z = {0.f, 0.f, 0.f, 0.f}; acc[f][g] = z; }

    gl_lds16(aLo,      S + tid * 8);
    gl_lds16(aHi,      S + 4096 + tid * 8);
    gl_lds16(bLo,      S + 16384 + tid * 8);
    gl_lds16(bHi,      S + 16384 + 4096 + tid * 8);
    gl_lds16(aLo + 32, S + 8192 + tid * 8);
    gl_lds16(aHi + 32, S + 8192 + 4096 + tid * 8);
    gl_lds16(bLo + 32, S + 24576 + tid * 8);
    gl_lds16(bHi + 32, S + 24576 + 4096 + tid * 8);
    asm volatile("s_waitcnt vmcnt(4)" ::: "memory");
    SBAR();

    for (int t = 0; t < NT; ++t) {
        unsigned short* Cb = S + (t & 1) * 32768;
        unsigned short* Nb = S + ((t & 1) ^ 1) * 32768;
        const int ts = (t + 1 == NT) ? 0 : t + 1;
        const int g0 = ts * 64;
        short8 bfr[4];
        // ---- phase 0 ----
        {
            short8 af[4];
#pragma unroll
            for (int f = 0; f < 4; f++) af[f] = *reinterpret_cast<const short8*>(&Cb[offA[f]]);
#pragma unroll
            for (int g = 0; g < 4; g++) bfr[g] = *reinterpret_cast<const short8*>(&Cb[16384 + offB[g]]);
            gl_lds16(aLo + g0, Nb + tid * 8);
            gl_lds16(aHi + g0, Nb + 4096 + tid * 8);
            LGKM0();
            __builtin_amdgcn_s_setprio(1);
#pragma unroll
            for (int f = 0; f < 4; f++)
#pragma unroll
                for (int g = 0; g < 4; g++)
                    acc[f][g] = __builtin_amdgcn_mfma_f32_16x16x32_bf16(af[f], bfr[g], acc[f][g], 0, 0, 0);
            __builtin_amdgcn_s_setprio(0);
            SBAR();
        }
        // ---- phase 1 ----
        {
            short8 af[4];
#pragma unroll
            for (int f = 0; f < 4; f++) af[f] = *reinterpret_cast<const short8*>(&Cb[offA[4 + f]]);
            gl_lds16(bLo + g0, Nb + 16384 + tid * 8);
            gl_lds16(bHi + g0, Nb + 16384 + 4096 + tid * 8);
            LGKM0();
            __builtin_amdgcn_s_setprio(1);
#pragma unroll
            for (int f = 0; f < 4; f++)
#pragma unroll
                for (int g = 0; g < 4; g++)
                    acc[4 + f][g] = __builtin_amdgcn_mfma_f32_16x16x32_bf16(af[f], bfr[g], acc[4 + f][g], 0, 0, 0);
            __builtin_amdgcn_s_setprio(0);
            asm volatile("s_waitcnt vmcnt(4)" ::: "memory");
            SBAR();
        }
        // ---- phase 2 ----
        {
            short8 af[4];
#pragma unroll
            for (int f = 0; f < 4; f++) af[f] = *reinterpret_cast<const short8*>(&Cb[8192 + offA[f]]);
#pragma unroll
            for (int g = 0; g < 4; g++) bfr[g] = *reinterpret_cast<const short8*>(&Cb[24576 + offB[g]]);
            gl_lds16(aLo + g0 + 32, Nb + 8192 + tid * 8);
            gl_lds16(aHi + g0 + 32, Nb + 8192 + 4096 + tid * 8);
            LGKM0();
            __builtin_amdgcn_s_setprio(1);
#pragma unroll
            for (int f = 0; f < 4; f++)
#pragma unroll
                for (int g = 0; g < 4; g++)
                    acc[f][g] = __builtin_amdgcn_mfma_f32_16x16x32_bf16(af[f], bfr[g], acc[f][g], 0, 0, 0);
            __builtin_amdgcn_s_setprio(0);
            SBAR();
        }
        // ---- phase 3 ----
        {
            short8 af[4];
#pragma unroll
            for (int f = 0; f < 4; f++) af[f] = *reinterpret_cast<const short8*>(&Cb[8192 + offA[4 + f]]);
            gl_lds16(bLo + g0 + 32, Nb + 24576 + tid * 8);
            gl_lds16(bHi + g0 + 32, Nb + 24576 + 4096 + tid * 8);
            LGKM0();
            __builtin_amdgcn_s_setprio(1);
#pragma unroll
            for (int f = 0; f < 4; f++)
#pragma unroll
                for (int g = 0; g < 4; g++)
                    acc[4 + f][g] = __builtin_amdgcn_mfma_f32_16x16x32_bf16(af[f], bfr[g], acc[4 + f][g], 0, 0, 0);
            __builtin_amdgcn_s_setprio(0);
            asm volatile("s_waitcnt vmcnt(4)" ::: "memory");
            SBAR();
        }
    }

    asm volatile("s_waitcnt vmcnt(0)" ::: "memory");   // drain dummies before epilogue

    float bias[4];
#pragma unroll
    for (int g = 0; g < 4; g++)
        bias[g] = (ks == 0) ? b2[e * CDIM + n0 + wc * 64 + g * 16 + lm] : 0.f;

#pragma unroll
    for (int f = 0; f < 8; f++) {
#pragma unroll
        for (int r = 0; r < 4; r++) {
            const int mrow = m0 + wr * 128 + f * 16 + kq * 4 + r;
            if (mrow < cnt) {
                const int tok = btok[e * TTOK + mrow];
                const float g8 = bgate[e * TTOK + mrow];
                float* orow = out + (size_t)tok * CDIM + n0;
#pragma unroll
                for (int g = 0; g < 4; g++)
                    atomicAdd(orow + wc * 64 + g * 16 + lm, g8 * (acc[f][g][r] + bias[g]));
            }
        }
    }
}

// ================= SLOW FALLBACK (round-1 kernels, in-loop fp32->bf16) =================

__global__ __launch_bounds__(256) void gemm1_kernel(
    const unsigned short* __restrict__ xb, const float* __restrict__ w1,
    const float* __restrict__ b1, const int* __restrict__ counts,
    const int* __restrict__ offsets, const int* __restrict__ btok,
    unsigned short* __restrict__ H) {
    const int e = blockIdx.z;
    const int cnt = counts[e];
    const int m0 = blockIdx.y * 128;
    if (m0 >= cnt) return;
    const int n0 = blockIdx.x * 128;
    const int po = offsets[e];

    __shared__ unsigned short As[128][32];
    __shared__ unsigned short Bs[128][32];

    const int tid = threadIdx.x;
    const int wave = tid >> 6, lane = tid & 63;
    const int wm = (wave >> 1) << 6, wn = (wave & 1) << 6;
    const int lm = lane & 15, kq = lane >> 4;

    f32x4 acc[4][4];
#pragma unroll
    for (int i = 0; i < 4; i++)
#pragma unroll
        for (int j = 0; j < 4; j++) { f32x4 z = {0.f, 0.f, 0.f, 0.f}; acc[i][j] = z; }

    const float* w1e = w1 + (size_t)e * FFDIM * CDIM;
    const int arow = tid >> 1;
    const int acolb = (tid & 1) * 16;
    int tokA = -1;
    if (m0 + arow < cnt) tokA = btok[e * TTOK + m0 + arow];
    const int brow = tid >> 1;
    const int bcol = (tid & 1) * 16;

    for (int k0 = 0; k0 < CDIM; k0 += 32) {
        uint4 a0 = {0, 0, 0, 0}, a1 = {0, 0, 0, 0};
        if (tokA >= 0) {
            const uint4* src = reinterpret_cast<const uint4*>(xb + (size_t)tokA * CDIM + k0 + acolb);
            a0 = src[0]; a1 = src[1];
        }
        *reinterpret_cast<uint4*>(&As[arow][acolb]) = a0;
        *reinterpret_cast<uint4*>(&As[arow][acolb + 8]) = a1;
        {
            const float* src = w1e + (size_t)(n0 + brow) * CDIM + k0 + bcol;
            ushort4* dst = reinterpret_cast<ushort4*>(&Bs[brow][bcol]);
#pragma unroll
            for (int q = 0; q < 4; q++) {
                float4 v = reinterpret_cast<const float4*>(src)[q];
                ushort4 o; o.x = f2bf(v.x); o.y = f2bf(v.y); o.z = f2bf(v.z); o.w = f2bf(v.w);
                dst[q] = o;
            }
        }
        __syncthreads();
        short8 af[4], bfr[4];
#pragma unroll
        for (int i = 0; i < 4; i++) af[i] = *reinterpret_cast<const short8*>(&As[wm + i * 16 + lm][kq * 8]);
#pragma unroll
        for (int j = 0; j < 4; j++) bfr[j] = *reinterpret_cast<const short8*>(&Bs[wn + j * 16 + lm][kq * 8]);
#pragma unroll
        for (int i = 0; i < 4; i++)
#pragma unroll
            for (int j = 0; j < 4; j++)
                acc[i][j] = __builtin_amdgcn_mfma_f32_16x16x32_bf16(af[i], bfr[j], acc[i][j], 0, 0, 0);
        __syncthreads();
    }

#pragma unroll
    for (int j = 0; j < 4; j++) {
        const int fcol = n0 + wn + j * 16 + lm;
        const float bias = b1[e * FFDIM + fcol];
#pragma unroll
        for (int i = 0; i < 4; i++) {
#pragma unroll
            for (int r = 0; r < 4; r++) {
                const int mrow = m0 + wm + i * 16 + kq * 4 + r;
                if (mrow < cnt) {
                    float h = acc[i][j][r] + bias;
                    float g = 0.5f * h * (1.f + erff(h * 0.70710678118654752f));
                    H[(size_t)(po + mrow) * FFDIM + fcol] = f2bf(g);
                }
            }
        }
    }
}

__global__ __launch_bounds__(256) void gemm2_kernel(
    const unsigned short* __restrict__ H, const float* __restrict__ w2,
    const float* __restrict__ b2, const int* __restrict__ counts,
    const int* __restrict__ offsets, const int* __restrict__ btok,
    const float* __restrict__ bgate, float* __restrict__ out) {
    const int e = blockIdx.z;
    const int cnt = counts[e];
    const int m0 = blockIdx.y * 128;
    if (m0 >= cnt) return;
    const int n0 = blockIdx.x * 128;
    const int po = offsets[e];

    __shared__ unsigned short As[128][32];
    __shared__ unsigned short Bs[128][32];

    const int tid = threadIdx.x;
    const int wave = tid >> 6, lane = tid & 63;
    const int wm = (wave >> 1) << 6, wn = (wave & 1) << 6;
    const int lm = lane & 15, kq = lane >> 4;

    f32x4 acc[4][4];
#pragma unroll
    for (int i = 0; i < 4; i++)
#pragma unroll
        for (int j = 0; j < 4; j++) { f32x4 z = {0.f, 0.f, 0.f, 0.f}; acc[i][j] = z; }

    const float* w2e = w2 + (size_t)e * CDIM * FFDIM;
    const int arow = tid >> 1;
    const int acolb = (tid & 1) * 16;
    const bool aval = (m0 + arow < cnt);
    const unsigned short* asrc = H + (size_t)(po + m0 + arow) * FFDIM + acolb;
    const int brow = tid >> 1;
    const int bcol = (tid & 1) * 16;

    for (int k0 = 0; k0 < FFDIM; k0 += 32) {
        uint4 a0 = {0, 0, 0, 0}, a1 = {0, 0, 0, 0};
        if (aval) {
            const uint4* src = reinterpret_cast<const uint4*>(asrc + k0);
            a0 = src[0]; a1 = src[1];
        }
        *reinterpret_cast<uint4*>(&As[arow][acolb]) = a0;
        *reinterpret_cast<uint4*>(&As[arow][acolb + 8]) = a1;
        {
            const float* src = w2e + (size_t)(n0 + brow) * FFDIM + k0 + bcol;
            ushort4* dst = reinterpret_cast<ushort4*>(&Bs[brow][bcol]);
#pragma unroll
            for (int q = 0; q < 4; q++) {
                float4 v = reinterpret_cast<const float4*>(src)[q];
                ushort4 o; o.x = f2bf(v.x); o.y = f2bf(v.y); o.z = f2bf(v.z); o.w = f2bf(v.w);
                dst[q] = o;
            }
        }
        __syncthreads();
        short8 af[4], bfr[4];
#pragma unroll
        for (int i = 0; i < 4; i++) af[i] = *reinterpret_cast<const short8*>(&As[wm + i * 16 + lm][kq * 8]);
#pragma unroll
        for (int j = 0; j < 4; j++) bfr[j] = *reinterpret_cast<const short8*>(&Bs[wn + j * 16 + lm][kq * 8]);
#pragma unroll
        for (int i = 0; i < 4; i++)
#pragma unroll
            for (int j = 0; j < 4; j++)
                acc[i][j] = __builtin_amdgcn_mfma_f32_16x16x32_bf16(af[i], bfr[j], acc[i][j], 0, 0, 0);
        __syncthreads();
    }

    float bias[4];
#pragma unroll
    for (int j = 0; j < 4; j++) bias[j] = b2[e * CDIM + n0 + wn + j * 16 + lm];

#pragma unroll
    for (int i = 0; i < 4; i++) {
#pragma unroll
        for (int r = 0; r < 4; r++) {
            const int mrow = m0 + wm + i * 16 + kq * 4 + r;
            if (mrow < cnt) {
                const int tok = btok[e * TTOK + mrow];
                const float g = bgate[e * TTOK + mrow];
                float* orow = out + (size_t)tok * CDIM;
#pragma unroll
                for (int j = 0; j < 4; j++) {
                    const int c = n0 + wn + j * 16 + lm;
                    atomicAdd(orow + c, g * (acc[i][j][r] + bias[j]));
                }
            }
        }
    }
}

extern "C" void kernel_launch(void* const* d_in, const int* in_sizes, int n_in,
                              void* d_out, int out_size, void* d_ws, size_t ws_size,
                              hipStream_t stream) {
    const float* x  = (const float*)d_in[0];
    const float* rw = (const float*)d_in[1];
    const float* w1 = (const float*)d_in[2];
    const float* b1 = (const float*)d_in[3];
    const float* w2 = (const float*)d_in[4];
    const float* b2 = (const float*)d_in[5];
    float* out = (float*)d_out;

    char* ws = (char*)d_ws;
    int*   counts  = (int*)ws;
    int*   offsets = (int*)(ws + 64);
    int*   btok    = (int*)(ws + 4096);
    float* bgate   = (float*)(ws + 4096 + 131072);

    hipMemsetAsync(d_out, 0, (size_t)out_size * sizeof(float), stream);
    hipMemsetAsync(counts, 0, 64, stream);

    const bool fast = ws_size >= ((size_t)137 << 20);

    if (fast) {
        unsigned short* xb = (unsigned short*)(ws + ((size_t)1 << 20));
        unsigned short* Wb = (unsigned short*)(ws + ((size_t)9 << 20));    // 64 MiB shared W1b/W2b
        unsigned short* H  = (unsigned short*)(ws + ((size_t)73 << 20));   // 64 MiB

        cast_kernel<<<(TTOK * CDIM) / (256 * 4), 256, 0, stream>>>(x, xb);
        router_kernel<<<TTOK / 4, 256, 0, stream>>>(x, rw, counts, btok, bgate);
        offsets_kernel<<<1, 64, 0, stream>>>(counts, offsets);
        cast_kernel<<<(NEXP * FFDIM * CDIM) / (256 * 4), 256, 0, stream>>>(w1, Wb);
        gemm1p8_kernel<<<dim3(FFDIM / 256, TTOK / 256, NEXP), 512, 0, stream>>>(
            xb, Wb, b1, counts, offsets, btok, H);
        cast_kernel<<<(NEXP * CDIM * FFDIM) / (256 * 4), 256, 0, stream>>>(w2, Wb);
        gemm2p8_kernel<<<dim3(CDIM / 256, (TTOK / 256) * 2, NEXP), 512, 0, stream>>>(
            H, Wb, b2, counts, offsets, btok, bgate, out);
    } else {
        unsigned short* xb = (unsigned short*)(ws + ((size_t)1 << 20));
        unsigned short* H  = (unsigned short*)(ws + ((size_t)16 << 20));

        cast_kernel<<<(TTOK * CDIM) / (256 * 4), 256, 0, stream>>>(x, xb);
        router_kernel<<<TTOK / 4, 256, 0, stream>>>(x, rw, counts, btok, bgate);
        offsets_kernel<<<1, 64, 0, stream>>>(counts, offsets);
        gemm1_kernel<<<dim3(FFDIM / 128, TTOK / 128, NEXP), 256, 0, stream>>>(
            xb, w1, b1, counts, offsets, btok, H);
        gemm2_kernel<<<dim3(CDIM / 128, TTOK / 128, NEXP), 256, 0, stream>>>(
            H, w2, b2, counts, offsets, btok, bgate, out);
    }
}